// Round 7
// baseline (301.131 us; speedup 1.0000x reference)
//
#include <hip/hip_runtime.h>

#define BB 256
#define LL 512
#define TT 128
#define CH 16  // staged steps per chunk

typedef _Float16 h2 __attribute__((ext_vector_type(2)));
typedef _Float16 f16x8 __attribute__((ext_vector_type(8)));
typedef float f32x4 __attribute__((ext_vector_type(4)));

#define MFMA16x32(A, B, C) __builtin_amdgcn_mfma_f32_16x16x32_f16((A), (B), (C), 0, 0, 0)

static __device__ inline h2 pkrtz(float a, float b) {
  return __builtin_bit_cast(h2, __builtin_amdgcn_cvt_pkrtz(a, b));
}

// Full 64-lane max (used for inits where all lanes hold distinct values).
static __device__ inline float wave_max_dpp(float x) {
  int v = __float_as_int(x);
#define DPP_STEP(ctrl)                                                  \
  {                                                                     \
    int t = __builtin_amdgcn_update_dpp(v, v, (ctrl), 0xf, 0xf, false); \
    x = fmaxf(x, __int_as_float(t));                                    \
    v = __float_as_int(x);                                              \
  }
  DPP_STEP(0x111) DPP_STEP(0x112) DPP_STEP(0x114) DPP_STEP(0x118)
  DPP_STEP(0x142) DPP_STEP(0x143)
#undef DPP_STEP
  return __int_as_float(__builtin_amdgcn_readlane(v, 63));
}

// 16-lane max: step values are duplicated across the 4 row-groups, so a
// row-local reduce suffices. 4 row_shr steps leave lane0 = max(lane 0..15).
static __device__ inline float wave_max16_dpp(float x) {
  int v = __float_as_int(x);
#define DPP_STEP(ctrl)                                                  \
  {                                                                     \
    int t = __builtin_amdgcn_update_dpp(v, v, (ctrl), 0xf, 0xf, false); \
    x = fmaxf(x, __int_as_float(t));                                    \
    v = __float_as_int(x);                                              \
  }
  DPP_STEP(0x111) DPP_STEP(0x112) DPP_STEP(0x114) DPP_STEP(0x118)
#undef DPP_STEP
  return __int_as_float(__builtin_amdgcn_readlane(v, 0));
}

static __device__ inline unsigned expbits(unsigned u) {
  return __float_as_uint(__expf(__uint_as_float(u)));
}

// MERGED-CHAIN kernel: ONE wave (wid0) runs BOTH the forward and backward
// recurrences, interleaved step-by-step with no barrier between them. The
// two chains are independent instruction streams, so each chain's serial
// latency (state LDS write->read round trip, 4-deep MFMA chains, DPP-max
// tail — the ~90% stall fraction measured in r6) is hidden under the
// OTHER chain's issue. Both E operand sets stay register-resident
// (64 f16x8 = 256 VGPRs; 1 wave/SIMD => full budget, MFMA reads AGPRs
// natively if the allocator overflows there). wid1/wid2 = emission
// stagers (exp-folded, double-buffered, verified r5 code) + numerator
// halves. Scale = exact pow2 bookkeeping as in all verified rounds.
__global__ __launch_bounds__(192)
__attribute__((amdgpu_waves_per_eu(1, 1)))
void crf_fb_kernel(const float* __restrict__ inputs,
                   const float* __restrict__ trans,
                   const float* __restrict__ start_t,
                   const float* __restrict__ end_t,
                   const int* __restrict__ tags,
                   const int* __restrict__ mask,
                   float* __restrict__ diff) {
  const int b = blockIdx.x;
  const int tid = threadIdx.x;
  const int lane = tid & 63;
  const int wid = tid >> 6;

  __shared__ __align__(16) float fbuf[2][CH * TT];  // fwd emissions, exp-folded
  __shared__ __align__(16) float bbuf[2][CH * TT];  // bwd emissions, exp-folded
  __shared__ __align__(16) h2 ef_lds[64];           // fwd state (128 halves)
  __shared__ __align__(16) h2 g_lds[64];            // bwd state (128 halves)
  __shared__ float numA_sh, numB_sh;

  // ---- each wave computes len ----
  int lm = 0;
  const int* mk = mask + b * LL;
#pragma unroll
  for (int q = 0; q < LL / 64; ++q) lm += mk[q * 64 + lane];
#pragma unroll
  for (int d = 1; d < 64; d <<= 1) lm += __shfl_xor(lm, d);
  const int len = lm;            // [256, 512]
  const int m = (len - 1) >> 1;  // meeting point; m >= 127
  const int K = len - 1 - m;     // bwd step count (= m or m+1)
  const int NC = (K + CH - 1) / CH;

  const float* erow = inputs + (size_t)b * LL * TT;
  const float2* er2 = (const float2*)erow;
  const int lg = lane >> 4, lc = lane & 15;

  // stage 16 rows (8 KB), folding exp() so the chain never computes it
  auto STAGE = [&](float* dst, const float* gbase) {
    const uint4* gs = (const uint4*)gbase;
    uint4* ds = (uint4*)dst;
    uint4 v[8];
#pragma unroll
    for (int q = 0; q < 8; ++q) v[q] = gs[q * 64 + lane];
#pragma unroll
    for (int q = 0; q < 8; ++q) {
      uint4 o;
      o.x = expbits(v[q].x);
      o.y = expbits(v[q].y);
      o.z = expbits(v[q].z);
      o.w = expbits(v[q].w);
      ds[q * 64 + lane] = o;
    }
  };

  int S_f = 0, S_b = 0;
  float isc_f = 1.0f, isc_b = 1.0f;
  int cex_f = 0, cex_b = 0;
  f16x8 EBf[8][4], EBb[8][4];  // B fragments, fwd / bwd orientations

  // ================= prologue =================
  if (wid == 0) {
    // fwd B: EBf[n][cc][jj] = exp(trans[32cc+8lg+jj][16n+lc])
#pragma unroll
    for (int n = 0; n < 8; ++n)
#pragma unroll
      for (int cc = 0; cc < 4; ++cc) {
        f16x8 e;
#pragma unroll
        for (int jj = 0; jj < 8; ++jj)
          e[jj] = (_Float16)__expf(trans[(32 * cc + 8 * lg + jj) * TT + 16 * n + lc]);
        EBf[n][cc] = e;
      }
    // bwd B: EBb[n][cc][jj] = exp(trans[16n+lc][32cc+8lg+jj]) (contiguous)
    const float4* tr4 = (const float4*)trans;
#pragma unroll
    for (int n = 0; n < 8; ++n)
#pragma unroll
      for (int cc = 0; cc < 4; ++cc) {
        int base = ((16 * n + lc) * TT + 32 * cc + 8 * lg) >> 2;
        float4 r0 = tr4[base], r1 = tr4[base + 1];
        f16x8 e;
        e[0] = (_Float16)__expf(r0.x);
        e[1] = (_Float16)__expf(r0.y);
        e[2] = (_Float16)__expf(r0.z);
        e[3] = (_Float16)__expf(r0.w);
        e[4] = (_Float16)__expf(r1.x);
        e[5] = (_Float16)__expf(r1.y);
        e[6] = (_Float16)__expf(r1.z);
        e[7] = (_Float16)__expf(r1.w);
        EBb[n][cc] = e;
      }
    // init fwd state
    float2 em0 = er2[lane];
    float f0 = __expf(start_t[2 * lane] + em0.x);
    float f1 = __expf(start_t[2 * lane + 1] + em0.y);
    ef_lds[lane] = pkrtz(f0, f1);
    float mxf = wave_max_dpp(fmaxf(f0, f1));
    int exf = (int)((__float_as_uint(mxf) >> 23) & 255) - 127;
    isc_f = __uint_as_float((unsigned)(120 - exf) << 23);
    cex_f = exf + 7;
    // init bwd state
    float2 em1 = er2[(size_t)(len - 1) * 64 + lane];
    float g0 = __expf(end_t[2 * lane] + em1.x);
    float g1 = __expf(end_t[2 * lane + 1] + em1.y);
    g_lds[lane] = pkrtz(g0, g1);
    float mxb = wave_max_dpp(fmaxf(g0, g1));
    int exb = (int)((__float_as_uint(mxb) >> 23) & 255) - 127;
    isc_b = __uint_as_float((unsigned)(120 - exb) << 23);
    cex_b = exb + 7;
  } else if (wid == 1) {
    STAGE(fbuf[0], erow + 1 * TT);  // fwd chunk 0: rows 1..16
    // numerator half A: t in [0, len/2)
    const int* tg = tags + (size_t)b * LL;
    const int hl = len >> 1;
    float sc = 0.f;
    for (int t = lane; t < hl; t += 64) {
      int cu = tg[t];
      sc += erow[(size_t)t * TT + cu];
      if (t >= 1) sc += trans[tg[t - 1] * TT + cu];
    }
    if (lane == 0) sc += start_t[tg[0]];
#pragma unroll
    for (int d = 1; d < 64; d <<= 1) sc += __shfl_xor(sc, d);
    if (lane == 0) numA_sh = sc;
  } else {
    STAGE(bbuf[0], erow + (size_t)(len - 1 - CH) * TT);  // bwd chunk 0
    // numerator half B: t in [len/2, len)
    const int* tg = tags + (size_t)b * LL;
    const int hl = len >> 1;
    float sc = 0.f;
    for (int t = hl + lane; t < len; t += 64) {
      int cu = tg[t];
      sc += erow[(size_t)t * TT + cu];
      sc += trans[tg[t - 1] * TT + cu];
    }
    if (lane == 0) sc += end_t[tg[len - 1]];
#pragma unroll
    for (int d = 1; d < 64; d <<= 1) sc += __shfl_xor(sc, d);
    if (lane == 0) numB_sh = sc;
  }

  __syncthreads();

  const f32x4 z4 = {0.f, 0.f, 0.f, 0.f};

  // one forward transition step (state in ef_lds, emissions exp-folded)
  auto FSTEP = [&](const float* fr) {
    float fv[8];
#pragma unroll
    for (int n = 0; n < 8; ++n) fv[n] = fr[16 * n + lc];
    const uint4* ep = (const uint4*)ef_lds;
    f16x8 A0 = __builtin_bit_cast(f16x8, ep[0 + lg]);
    f16x8 A1 = __builtin_bit_cast(f16x8, ep[4 + lg]);
    f16x8 A2 = __builtin_bit_cast(f16x8, ep[8 + lg]);
    f16x8 A3 = __builtin_bit_cast(f16x8, ep[12 + lg]);
    f32x4 acc[8];
#pragma unroll
    for (int n = 0; n < 8; ++n) acc[n] = MFMA16x32(A0, EBf[n][0], z4);
#pragma unroll
    for (int n = 0; n < 8; ++n) acc[n] = MFMA16x32(A1, EBf[n][1], acc[n]);
#pragma unroll
    for (int n = 0; n < 8; ++n) acc[n] = MFMA16x32(A2, EBf[n][2], acc[n]);
#pragma unroll
    for (int n = 0; n < 8; ++n) acc[n] = MFMA16x32(A3, EBf[n][3], acc[n]);
    float w[8];
#pragma unroll
    for (int n = 0; n < 8; ++n) w[n] = acc[n][0] * (fv[n] * isc_f);
    float wm = fmaxf(fmaxf(fmaxf(w[0], w[1]), fmaxf(w[2], w[3])),
                     fmaxf(fmaxf(w[4], w[5]), fmaxf(w[6], w[7])));
    if (lane < 16) {
      _Float16* sp = (_Float16*)ef_lds;
#pragma unroll
      for (int n = 0; n < 8; ++n) sp[16 * n + lc] = pkrtz(w[n], w[n]).x;
    }
    S_f += cex_f;
    float mx = wave_max16_dpp(wm);
    int exm = (int)((__float_as_uint(mx) >> 23) & 255) - 127;
    isc_f = __uint_as_float((unsigned)(120 - exm) << 23);
    cex_f = exm + 7;
  };

  // one backward transition step
  auto BSTEP = [&](const float* pr, bool fold) {
    float pv[8];
#pragma unroll
    for (int n = 0; n < 8; ++n) pv[n] = pr[16 * n + lc];
    const uint4* gp = (const uint4*)g_lds;
    f16x8 A0 = __builtin_bit_cast(f16x8, gp[0 + lg]);
    f16x8 A1 = __builtin_bit_cast(f16x8, gp[4 + lg]);
    f16x8 A2 = __builtin_bit_cast(f16x8, gp[8 + lg]);
    f16x8 A3 = __builtin_bit_cast(f16x8, gp[12 + lg]);
    f32x4 acc[8];
#pragma unroll
    for (int n = 0; n < 8; ++n) acc[n] = MFMA16x32(A0, EBb[n][0], z4);
#pragma unroll
    for (int n = 0; n < 8; ++n) acc[n] = MFMA16x32(A1, EBb[n][1], acc[n]);
#pragma unroll
    for (int n = 0; n < 8; ++n) acc[n] = MFMA16x32(A2, EBb[n][2], acc[n]);
#pragma unroll
    for (int n = 0; n < 8; ++n) acc[n] = MFMA16x32(A3, EBb[n][3], acc[n]);
    float w[8];
    if (fold) {
#pragma unroll
      for (int n = 0; n < 8; ++n) w[n] = acc[n][0] * (pv[n] * isc_b);
    } else {
#pragma unroll
      for (int n = 0; n < 8; ++n) w[n] = acc[n][0] * isc_b;
    }
    float wm = fmaxf(fmaxf(fmaxf(w[0], w[1]), fmaxf(w[2], w[3])),
                     fmaxf(fmaxf(w[4], w[5]), fmaxf(w[6], w[7])));
    if (lane < 16) {
      _Float16* sp = (_Float16*)g_lds;
#pragma unroll
      for (int n = 0; n < 8; ++n) sp[16 * n + lc] = pkrtz(w[n], w[n]).x;
    }
    S_b += cex_b;
    float mx = wave_max16_dpp(wm);
    int exm = (int)((__float_as_uint(mx) >> 23) & 255) - 127;
    isc_b = __uint_as_float((unsigned)(120 - exm) << 23);
    cex_b = exm + 7;
  };

  // ================= chunk loop =================
  for (int c = 0; c < NC; ++c) {
    if (wid == 0) {
      const float* fb = fbuf[c & 1];
      const float* bbm = bbuf[c & 1];
      const int tbeg = 1 + CH * c;
      int tf = tbeg;
      const int tfe = min(CH * (c + 1), m);
      const int lb = len - 1 - CH * (c + 1);
      int tb = len - 2 - CH * c;
      const int tbe = max(m, lb);
      int nf = tfe - tf + 1;
      int nb = tb - tbe + 1;
      int np = nf < nb ? nf : nb;
      if (np < 0) np = 0;
#pragma unroll 1
      for (int k = 0; k < np; ++k) {
        FSTEP(fb + (tf - tbeg) * TT);
        ++tf;
        BSTEP(bbm + (tb - lb) * TT, tb > m);
        --tb;
      }
#pragma unroll 1
      for (; tf <= tfe; ++tf) FSTEP(fb + (tf - tbeg) * TT);
#pragma unroll 1
      for (; tb >= tbe; --tb) BSTEP(bbm + (tb - lb) * TT, tb > m);
    } else if (wid == 1) {
      if (c + 1 < NC) STAGE(fbuf[(c + 1) & 1], erow + (size_t)(1 + CH * (c + 1)) * TT);
    } else {
      if (c + 1 < NC) STAGE(bbuf[(c + 1) & 1], erow + (size_t)(len - 1 - CH * (c + 2)) * TT);
    }
    __syncthreads();
  }

  // ================= epilogue =================
  if (wid == 0) {
    h2 a = ef_lds[lane];
    h2 g = g_lds[lane];
    float v = (float)a.x * (float)g.x + (float)a.y * (float)g.y;
#pragma unroll
    for (int d = 1; d < 64; d <<= 1) v += __shfl_xor(v, d);
    if (lane == 0) {
      float log_den = (float)(S_f + S_b) * 0.6931471805599453f + __logf(v);
      diff[b] = (numA_sh + numB_sh) - log_den;
    }
  }
}

// Deterministic final reduction over batch.
__global__ void crf_sum_kernel(const float* __restrict__ diff,
                               float* __restrict__ out) {
  const int tid = threadIdx.x;  // 256
  float v = diff[tid];
#pragma unroll
  for (int d = 1; d < 64; d <<= 1) v += __shfl_xor(v, d);
  __shared__ float r[4];
  if ((tid & 63) == 0) r[tid >> 6] = v;
  __syncthreads();
  if (tid == 0) out[0] = r[0] + r[1] + r[2] + r[3];
}

extern "C" void kernel_launch(void* const* d_in, const int* in_sizes, int n_in,
                              void* d_out, int out_size, void* d_ws, size_t ws_size,
                              hipStream_t stream) {
  const float* inputs = (const float*)d_in[0];
  const float* trans = (const float*)d_in[1];
  const float* start_t = (const float*)d_in[2];
  const float* end_t = (const float*)d_in[3];
  const int* tags = (const int*)d_in[4];
  const int* mask = (const int*)d_in[5];
  float* diff = (float*)d_ws;  // 256 floats
  float* out = (float*)d_out;

  crf_fb_kernel<<<BB, 192, 0, stream>>>(inputs, trans, start_t, end_t, tags,
                                        mask, diff);
  crf_sum_kernel<<<1, 256, 0, stream>>>(diff, out);
}

// Round 8
// 135.852 us; speedup vs baseline: 2.2166x; 2.2166x over previous
//
#include <hip/hip_runtime.h>
#include <hip/hip_bf16.h>

#define BB 256
#define LL 512
#define TT 128
#define CH 16  // staged steps per chunk

typedef _Float16 h2 __attribute__((ext_vector_type(2)));
typedef unsigned int u32;

static __device__ inline h2 pkrtz(float a, float b) {
  return __builtin_bit_cast(h2, __builtin_amdgcn_cvt_pkrtz(a, b));
}

#if defined(__has_builtin)
#if __has_builtin(__builtin_amdgcn_fdot2)
#define FDOT2(a, b, c) __builtin_amdgcn_fdot2((a), (b), (c), false)
#endif
#endif
#ifndef FDOT2
static __device__ inline float fdot2_fb(h2 a, h2 b, float c) {
  return fmaf((float)a.x, (float)b.x, fmaf((float)a.y, (float)b.y, c));
}
#define FDOT2(a, b, c) fdot2_fb((a), (b), (c))
#endif

static __device__ inline h2 bch2(unsigned u) { return __builtin_bit_cast(h2, u); }

// Full-wave max via DPP (VALU pipe only — off the LDS queue).
static __device__ inline float wave_max_dpp(float x) {
  int v = __float_as_int(x);
#define DPP_STEP(ctrl)                                                  \
  {                                                                     \
    int t = __builtin_amdgcn_update_dpp(v, v, (ctrl), 0xf, 0xf, false); \
    x = fmaxf(x, __int_as_float(t));                                    \
    v = __float_as_int(x);                                              \
  }
  DPP_STEP(0x111)
  DPP_STEP(0x112)
  DPP_STEP(0x114)
  DPP_STEP(0x118)
  DPP_STEP(0x142)
  DPP_STEP(0x143)
#undef DPP_STEP
  return __int_as_float(__builtin_amdgcn_readlane(v, 63));
}

// Round-0 champion kernel with ONE change: the per-output dot
// accumulation is split from 8 chains x 16-deep into 16 chains x 8-deep
// (a0..a7 / c0..c7, each accumulating 8 stride-8 terms, combined by a
// 3-level add tree). Rationale: r0/r3/r5 all land at ~1080 cy/step across
// three different broadcast mechanisms and instruction counts, with issue
// accounting for only ~350 cy — the common serial structure is the
// 16-deep dependent fdot2 chain (16 x ~45 cy ~= the unexplained ~730 cy).
// Halving chain depth probes (and if correct, removes) ~360 cy/step.
// Everything else — stagers, chunk barriers, LDS state broadcast,
// in-chain exp, exact pow2 scale bookkeeping — is byte-identical to r0.
__global__ __launch_bounds__(256)
__attribute__((amdgpu_waves_per_eu(1, 1)))
void crf_fb_kernel(const float* __restrict__ inputs,
                   const float* __restrict__ trans,
                   const float* __restrict__ start_t,
                   const float* __restrict__ end_t,
                   const int* __restrict__ tags,
                   const int* __restrict__ mask,
                   float* __restrict__ diff) {
  const int b = blockIdx.x;
  const int tid = threadIdx.x;
  const int lane = tid & 63;
  const int wid = tid >> 6;

  __shared__ __align__(16) float fbuf[2][CH * TT];  // fwd emission chunks
  __shared__ __align__(16) float bbuf[2][CH * TT];  // bwd emission chunks
  __shared__ __align__(16) h2 ef_lds[64];           // forward state
  __shared__ __align__(16) h2 g_lds[64];            // backward state
  __shared__ float numA_sh, numB_sh;
  __shared__ int sb_sh;

  // ---- each wave computes len ----
  int lm = 0;
  const int* mk = mask + b * LL;
#pragma unroll
  for (int q = 0; q < LL / 64; ++q) lm += mk[q * 64 + lane];
#pragma unroll
  for (int d = 1; d < 64; d <<= 1) lm += __shfl_xor(lm, d);
  const int len = lm;            // [256, 512]
  const int m = (len - 1) >> 1;  // meeting point; m >= 127
  const int NC = (len - 1 - m + CH - 1) / CH;  // chunks (bwd has max steps)

  const float* erow = inputs + (size_t)b * LL * TT;
  const float2* er2 = (const float2*)erow;
  const float2* tr2 = (const float2*)trans;

  // stage 16 rows (8 KB) from gbase into dst via registers (full unroll)
  auto STAGE = [&](float* dst, const float* gbase) {
    const uint4* gs = (const uint4*)gbase;
    uint4* ds = (uint4*)dst;
    uint4 v0 = gs[0 * 64 + lane], v1 = gs[1 * 64 + lane];
    uint4 v2 = gs[2 * 64 + lane], v3 = gs[3 * 64 + lane];
    uint4 v4 = gs[4 * 64 + lane], v5 = gs[5 * 64 + lane];
    uint4 v6 = gs[6 * 64 + lane], v7 = gs[7 * 64 + lane];
    ds[0 * 64 + lane] = v0;
    ds[1 * 64 + lane] = v1;
    ds[2 * 64 + lane] = v2;
    ds[3 * 64 + lane] = v3;
    ds[4 * 64 + lane] = v4;
    ds[5 * 64 + lane] = v5;
    ds[6 * 64 + lane] = v6;
    ds[7 * 64 + lane] = v7;
  };

  int S = 0;
  float inv_sc = 1.0f;
  int cur_ex = 0;
  h2 Ea0[64], Ea1[64];  // E fragments (fwd: col-pairs; bwd: row-pairs)

  // ================= prologue =================
  if (wid == 0) {
#pragma unroll
    for (int p = 0; p < 64; ++p) {
      float2 r0 = tr2[(2 * p) * 64 + lane];      // row 2p, cols j0,j1
      float2 r1 = tr2[(2 * p + 1) * 64 + lane];  // row 2p+1
      h2 c0, c1;
      c0.x = (_Float16)__expf(r0.x);
      c0.y = (_Float16)__expf(r1.x);
      c1.x = (_Float16)__expf(r0.y);
      c1.y = (_Float16)__expf(r1.y);
      Ea0[p] = c0;
      Ea1[p] = c1;
    }
    float2 em0 = er2[lane];
    float f0 = __expf(start_t[2 * lane] + em0.x);
    float f1 = __expf(start_t[2 * lane + 1] + em0.y);
    ef_lds[lane] = pkrtz(f0, f1);
    float mx = wave_max_dpp(fmaxf(f0, f1));
    int exm = (int)((__float_as_uint(mx) >> 23) & 255) - 127;
    inv_sc = __uint_as_float((unsigned)(120 - exm) << 23);
    cur_ex = exm + 7;
  } else if (wid == 1) {
#pragma unroll
    for (int p = 0; p < 64; ++p) {
      float2 r0 = tr2[(2 * lane) * 64 + p];
      float2 r1 = tr2[(2 * lane + 1) * 64 + p];
      h2 c0, c1;
      c0.x = (_Float16)__expf(r0.x);
      c0.y = (_Float16)__expf(r0.y);
      c1.x = (_Float16)__expf(r1.x);
      c1.y = (_Float16)__expf(r1.y);
      Ea0[p] = c0;
      Ea1[p] = c1;
    }
    float2 em = er2[(size_t)(len - 1) * 64 + lane];
    float g0 = __expf(end_t[2 * lane] + em.x);
    float g1 = __expf(end_t[2 * lane + 1] + em.y);
    g_lds[lane] = pkrtz(g0, g1);
    float mx = wave_max_dpp(fmaxf(g0, g1));
    int exm = (int)((__float_as_uint(mx) >> 23) & 255) - 127;
    inv_sc = __uint_as_float((unsigned)(120 - exm) << 23);
    cur_ex = exm + 7;
  } else if (wid == 2) {
    STAGE(fbuf[0], erow + 1 * TT);  // fwd chunk 0: rows 1..16
    // numerator half A: t in [0, len/2)
    const int* tg = tags + (size_t)b * LL;
    const int hl = len >> 1;
    float sc = 0.f;
    for (int t = lane; t < hl; t += 64) {
      int cu = tg[t];
      sc += erow[(size_t)t * TT + cu];
      if (t >= 1) sc += trans[tg[t - 1] * TT + cu];
    }
    if (lane == 0) sc += start_t[tg[0]];
#pragma unroll
    for (int d = 1; d < 64; d <<= 1) sc += __shfl_xor(sc, d);
    if (lane == 0) numA_sh = sc;
  } else {
    STAGE(bbuf[0], erow + (size_t)(len - 1 - CH) * TT);  // bwd chunk 0
    // numerator half B: t in [len/2, len)
    const int* tg = tags + (size_t)b * LL;
    const int hl = len >> 1;
    float sc = 0.f;
    for (int t = hl + lane; t < len; t += 64) {
      int cu = tg[t];
      sc += erow[(size_t)t * TT + cu];
      sc += trans[tg[t - 1] * TT + cu];
    }
    if (lane == 0) sc += end_t[tg[len - 1]];
#pragma unroll
    for (int d = 1; d < 64; d <<= 1) sc += __shfl_xor(sc, d);
    if (lane == 0) numB_sh = sc;
  }

  __syncthreads();

  // ================= chunk loop =================
  for (int c = 0; c < NC; ++c) {
    if (wid == 0) {
      // ---- forward chain steps of chunk c ----
      const float2* emb = (const float2*)fbuf[c & 1];
      const int tbeg = 1 + CH * c;
      const int tend = min(tbeg + CH - 1, m);
#pragma unroll 1
      for (int t = tbeg; t <= tend; ++t) {
        float2 em = emb[(t - tbeg) * 64 + lane];
        float f0 = __expf(em.x) * inv_sc;
        float f1 = __expf(em.y) * inv_sc;
        float a0 = 0.f, a1 = 0.f, a2 = 0.f, a3 = 0.f;
        float a4 = 0.f, a5 = 0.f, a6 = 0.f, a7 = 0.f;
        float c0 = 0.f, c1 = 0.f, c2 = 0.f, c3 = 0.f;
        float c4 = 0.f, c5 = 0.f, c6 = 0.f, c7 = 0.f;
        const uint4* ep = (const uint4*)ef_lds;
#pragma unroll
        for (int r = 0; r < 8; ++r) {
          uint4 q0 = ep[2 * r];  // broadcast reads, conflict-free
          uint4 q1 = ep[2 * r + 1];
          h2 e0 = bch2(q0.x), e1 = bch2(q0.y), e2 = bch2(q0.z), e3 = bch2(q0.w);
          h2 e4 = bch2(q1.x), e5 = bch2(q1.y), e6 = bch2(q1.z), e7 = bch2(q1.w);
          a0 = FDOT2(e0, Ea0[8 * r + 0], a0);
          a1 = FDOT2(e1, Ea0[8 * r + 1], a1);
          a2 = FDOT2(e2, Ea0[8 * r + 2], a2);
          a3 = FDOT2(e3, Ea0[8 * r + 3], a3);
          a4 = FDOT2(e4, Ea0[8 * r + 4], a4);
          a5 = FDOT2(e5, Ea0[8 * r + 5], a5);
          a6 = FDOT2(e6, Ea0[8 * r + 6], a6);
          a7 = FDOT2(e7, Ea0[8 * r + 7], a7);
          c0 = FDOT2(e0, Ea1[8 * r + 0], c0);
          c1 = FDOT2(e1, Ea1[8 * r + 1], c1);
          c2 = FDOT2(e2, Ea1[8 * r + 2], c2);
          c3 = FDOT2(e3, Ea1[8 * r + 3], c3);
          c4 = FDOT2(e4, Ea1[8 * r + 4], c4);
          c5 = FDOT2(e5, Ea1[8 * r + 5], c5);
          c6 = FDOT2(e6, Ea1[8 * r + 6], c6);
          c7 = FDOT2(e7, Ea1[8 * r + 7], c7);
        }
        float w0 = (((a0 + a1) + (a2 + a3)) + ((a4 + a5) + (a6 + a7))) * f0;
        float w1 = (((c0 + c1) + (c2 + c3)) + ((c4 + c5) + (c6 + c7))) * f1;
        ef_lds[lane] = pkrtz(w0, w1);
        S += cur_ex;
        float mx = wave_max_dpp(fmaxf(w0, w1));
        int exm = (int)((__float_as_uint(mx) >> 23) & 255) - 127;
        inv_sc = __uint_as_float((unsigned)(120 - exm) << 23);
        cur_ex = exm + 7;
      }
    } else if (wid == 1) {
      // ---- backward chain steps of chunk c ----
      const int thi = len - 2 - CH * c;
      const int lb = len - 1 - CH * (c + 1);  // staged base row
      const int tlo = max(m, lb);
      const float2* emb = (const float2*)bbuf[c & 1];
#pragma unroll 1
      for (int t = thi; t >= tlo; --t) {
        float2 em = emb[(t - lb) * 64 + lane];
        float pex0 = __expf(em.x);
        float pex1 = __expf(em.y);
        float a0 = 0.f, a1 = 0.f, a2 = 0.f, a3 = 0.f;
        float a4 = 0.f, a5 = 0.f, a6 = 0.f, a7 = 0.f;
        float c0 = 0.f, c1 = 0.f, c2 = 0.f, c3 = 0.f;
        float c4 = 0.f, c5 = 0.f, c6 = 0.f, c7 = 0.f;
        const uint4* gp = (const uint4*)g_lds;
#pragma unroll
        for (int r = 0; r < 8; ++r) {
          uint4 q0 = gp[2 * r];
          uint4 q1 = gp[2 * r + 1];
          h2 e0 = bch2(q0.x), e1 = bch2(q0.y), e2 = bch2(q0.z), e3 = bch2(q0.w);
          h2 e4 = bch2(q1.x), e5 = bch2(q1.y), e6 = bch2(q1.z), e7 = bch2(q1.w);
          a0 = FDOT2(e0, Ea0[8 * r + 0], a0);
          a1 = FDOT2(e1, Ea0[8 * r + 1], a1);
          a2 = FDOT2(e2, Ea0[8 * r + 2], a2);
          a3 = FDOT2(e3, Ea0[8 * r + 3], a3);
          a4 = FDOT2(e4, Ea0[8 * r + 4], a4);
          a5 = FDOT2(e5, Ea0[8 * r + 5], a5);
          a6 = FDOT2(e6, Ea0[8 * r + 6], a6);
          a7 = FDOT2(e7, Ea0[8 * r + 7], a7);
          c0 = FDOT2(e0, Ea1[8 * r + 0], c0);
          c1 = FDOT2(e1, Ea1[8 * r + 1], c1);
          c2 = FDOT2(e2, Ea1[8 * r + 2], c2);
          c3 = FDOT2(e3, Ea1[8 * r + 3], c3);
          c4 = FDOT2(e4, Ea1[8 * r + 4], c4);
          c5 = FDOT2(e5, Ea1[8 * r + 5], c5);
          c6 = FDOT2(e6, Ea1[8 * r + 6], c6);
          c7 = FDOT2(e7, Ea1[8 * r + 7], c7);
        }
        float v0 = ((a0 + a1) + (a2 + a3)) + ((a4 + a5) + (a6 + a7));
        float v1 = ((c0 + c1) + (c2 + c3)) + ((c4 + c5) + (c6 + c7));
        if (t > m) {  // fold exp(emit_t); at t==m store raw
          v0 *= pex0;
          v1 *= pex1;
        }
        float w0 = v0 * inv_sc, w1 = v1 * inv_sc;
        g_lds[lane] = pkrtz(w0, w1);
        S += cur_ex;
        float mx = wave_max_dpp(fmaxf(w0, w1));
        int exm = (int)((__float_as_uint(mx) >> 23) & 255) - 127;
        inv_sc = __uint_as_float((unsigned)(120 - exm) << 23);
        cur_ex = exm + 7;
      }
    } else if (wid == 2) {
      if (c + 1 < NC) STAGE(fbuf[(c + 1) & 1], erow + (size_t)(1 + CH * (c + 1)) * TT);
    } else {
      if (c + 1 < NC) STAGE(bbuf[(c + 1) & 1], erow + (size_t)(len - 1 - CH * (c + 2)) * TT);
    }
    __syncthreads();
  }

  if (wid == 1 && lane == 0) sb_sh = S;
  __syncthreads();

  if (wid == 0) {
    h2 a = ef_lds[lane];
    h2 g = g_lds[lane];
    float v = (float)a.x * (float)g.x + (float)a.y * (float)g.y;
#pragma unroll
    for (int d = 1; d < 64; d <<= 1) v += __shfl_xor(v, d);
    if (lane == 0) {
      float log_den = (float)(S + sb_sh) * 0.6931471805599453f + __logf(v);
      diff[b] = (numA_sh + numB_sh) - log_den;
    }
  }
}

// Deterministic final reduction over batch.
__global__ void crf_sum_kernel(const float* __restrict__ diff,
                               float* __restrict__ out) {
  const int tid = threadIdx.x;  // 256
  float v = diff[tid];
#pragma unroll
  for (int d = 1; d < 64; d <<= 1) v += __shfl_xor(v, d);
  __shared__ float r[4];
  if ((tid & 63) == 0) r[tid >> 6] = v;
  __syncthreads();
  if (tid == 0) out[0] = r[0] + r[1] + r[2] + r[3];
}

extern "C" void kernel_launch(void* const* d_in, const int* in_sizes, int n_in,
                              void* d_out, int out_size, void* d_ws, size_t ws_size,
                              hipStream_t stream) {
  const float* inputs = (const float*)d_in[0];
  const float* trans = (const float*)d_in[1];
  const float* start_t = (const float*)d_in[2];
  const float* end_t = (const float*)d_in[3];
  const int* tags = (const int*)d_in[4];
  const int* mask = (const int*)d_in[5];
  float* diff = (float*)d_ws;  // 256 floats
  float* out = (float*)d_out;

  crf_fb_kernel<<<BB, 256, 0, stream>>>(inputs, trans, start_t, end_t, tags,
                                        mask, diff);
  crf_sum_kernel<<<1, 256, 0, stream>>>(diff, out);
}